// Round 1
// baseline (12278.629 us; speedup 1.0000x reference)
//
#include <hip/hip_runtime.h>

#define NUM_USERS 100000
#define NUM_ITEMS 50000
#define NNODES    150000
#define EMB       64
#define NEDGES    4800000
#define BATCH     4096

// cur/acc init: concat(user_emb, item_emb) into both buffers, float4 vectorized.
__global__ void init_kernel(const float* __restrict__ user_emb,
                            const float* __restrict__ item_emb,
                            float* __restrict__ cur, float* __restrict__ acc) {
    long i = (long)blockIdx.x * blockDim.x + threadIdx.x;   // float4 units
    const long n4 = (long)NNODES * EMB / 4;
    if (i >= n4) return;
    const long nu4 = (long)NUM_USERS * EMB / 4;
    float4 v = (i < nu4) ? ((const float4*)user_emb)[i]
                         : ((const float4*)item_emb)[i - nu4];
    ((float4*)cur)[i] = v;
    ((float4*)acc)[i] = v;
}

// COO SpMM via atomics: 16 threads per edge, thread t handles dims [4t, 4t+4).
__global__ void spmm_atomic(const int* __restrict__ rows,
                            const int* __restrict__ cols,
                            const float* __restrict__ vals,
                            const float* __restrict__ cur,
                            float* __restrict__ next) {
    long tid = (long)blockIdx.x * blockDim.x + threadIdx.x;
    long e = tid >> 4;
    int  t = (int)(tid & 15);
    if (e >= NEDGES) return;
    int   r = rows[e];
    int   c = cols[e];
    float v = vals[e];
    float4 x = ((const float4*)(cur + (long)c * EMB))[t];
    float* dst = next + (long)r * EMB + t * 4;
    atomicAdd(dst + 0, v * x.x);
    atomicAdd(dst + 1, v * x.y);
    atomicAdd(dst + 2, v * x.z);
    atomicAdd(dst + 3, v * x.w);
}

// acc += next (float4 vectorized)
__global__ void accum_kernel(const float* __restrict__ next, float* __restrict__ acc) {
    long i = (long)blockIdx.x * blockDim.x + threadIdx.x;   // float4 units
    const long n4 = (long)NNODES * EMB / 4;
    if (i >= n4) return;
    float4 a = ((const float4*)acc)[i];
    float4 b = ((const float4*)next)[i];
    a.x += b.x; a.y += b.y; a.z += b.z; a.w += b.w;
    ((float4*)acc)[i] = a;
}

// One wave (64 lanes) per batch element; lane = embedding dim.
// pos = dot(acc_u, acc_p)/16, neg = dot(acc_u, acc_n)/16  (final = acc/4)
__global__ void score_kernel(const int* __restrict__ users,
                             const int* __restrict__ pos_items,
                             const int* __restrict__ neg_items,
                             const float* __restrict__ acc,
                             float* __restrict__ out) {
    int gtid = blockIdx.x * blockDim.x + threadIdx.x;
    int wave = gtid >> 6;
    int lane = threadIdx.x & 63;
    if (wave >= BATCH) return;
    int u = users[wave];
    int p = pos_items[wave] + NUM_USERS;
    int n = neg_items[wave] + NUM_USERS;
    float ue = acc[(long)u * EMB + lane];
    float pe = acc[(long)p * EMB + lane];
    float ne = acc[(long)n * EMB + lane];
    float ps = ue * pe;
    float ns = ue * ne;
    #pragma unroll
    for (int off = 32; off > 0; off >>= 1) {
        ps += __shfl_down(ps, off, 64);
        ns += __shfl_down(ns, off, 64);
    }
    if (lane == 0) {
        out[wave]         = ps * 0.0625f;
        out[BATCH + wave] = ns * 0.0625f;
    }
}

extern "C" void kernel_launch(void* const* d_in, const int* in_sizes, int n_in,
                              void* d_out, int out_size, void* d_ws, size_t ws_size,
                              hipStream_t stream) {
    const int*   users = (const int*)d_in[0];
    const int*   pos   = (const int*)d_in[1];
    const int*   neg   = (const int*)d_in[2];
    const int*   rows  = (const int*)d_in[3];
    const int*   cols  = (const int*)d_in[4];
    const float* vals  = (const float*)d_in[5];
    const float* uemb  = (const float*)d_in[6];
    const float* iemb  = (const float*)d_in[7];
    float* out = (float*)d_out;

    const size_t bufElems = (size_t)NNODES * EMB;   // 9.6M floats = 38.4 MB
    float* bufA = (float*)d_ws;          // cur
    float* bufB = bufA + bufElems;       // next
    float* acc  = bufB + bufElems;       // accumulator

    const long n4 = (long)bufElems / 4;
    init_kernel<<<(int)((n4 + 255) / 256), 256, 0, stream>>>(uemb, iemb, bufA, acc);

    float* cur = bufA;
    float* nxt = bufB;
    for (int l = 0; l < 3; ++l) {
        hipMemsetAsync(nxt, 0, bufElems * sizeof(float), stream);
        const long nth = (long)NEDGES * 16;
        spmm_atomic<<<(int)((nth + 255) / 256), 256, 0, stream>>>(rows, cols, vals, cur, nxt);
        accum_kernel<<<(int)((n4 + 255) / 256), 256, 0, stream>>>(nxt, acc);
        float* t = cur; cur = nxt; nxt = t;
    }

    score_kernel<<<(BATCH * 64) / 256, 256, 0, stream>>>(users, pos, neg, acc, out);
}

// Round 2
// 1106.401 us; speedup vs baseline: 11.0978x; 11.0978x over previous
//
#include <hip/hip_runtime.h>

#define NUM_USERS 100000
#define NUM_ITEMS 50000
#define NNODES    150000
#define EMB       64
#define NEDGES    4800000
#define BATCH     4096
#define NB        586           // ceil(NNODES/256)

// cur/acc init: concat(user_emb, item_emb) into both buffers, float4 vectorized.
__global__ void init_kernel(const float* __restrict__ user_emb,
                            const float* __restrict__ item_emb,
                            float* __restrict__ cur, float* __restrict__ acc) {
    long i = (long)blockIdx.x * blockDim.x + threadIdx.x;   // float4 units
    const long n4 = (long)NNODES * EMB / 4;
    if (i >= n4) return;
    const long nu4 = (long)NUM_USERS * EMB / 4;
    float4 v = (i < nu4) ? ((const float4*)user_emb)[i]
                         : ((const float4*)item_emb)[i - nu4];
    ((float4*)cur)[i] = v;
    ((float4*)acc)[i] = v;
}

// --- CSR build ---------------------------------------------------------

__global__ void hist_kernel(const int* __restrict__ rows, int* __restrict__ counts) {
    int e = blockIdx.x * blockDim.x + threadIdx.x;
    if (e < NEDGES) atomicAdd(&counts[rows[e]], 1);
}

// per-256-block sums of counts
__global__ void scanA(const int* __restrict__ counts, int* __restrict__ blkSums) {
    int i = blockIdx.x * 256 + threadIdx.x;
    int c = (i < NNODES) ? counts[i] : 0;
    #pragma unroll
    for (int d = 32; d > 0; d >>= 1) c += __shfl_down(c, d, 64);
    __shared__ int wsum[4];
    int lane = threadIdx.x & 63, w = threadIdx.x >> 6;
    if (lane == 0) wsum[w] = c;
    __syncthreads();
    if (threadIdx.x == 0)
        blkSums[blockIdx.x] = wsum[0] + wsum[1] + wsum[2] + wsum[3];
}

// exclusive scan of blkSums in place (single wave, chunks of 64 with carry)
__global__ void scanB(int* __restrict__ blk) {
    int lane = threadIdx.x;
    int carry = 0;
    for (int base = 0; base < NB; base += 64) {
        int i = base + lane;
        int orig = (i < NB) ? blk[i] : 0;
        int x = orig;
        #pragma unroll
        for (int d = 1; d < 64; d <<= 1) {
            int t = __shfl_up(x, d, 64);
            if (lane >= d) x += t;
        }
        int total = __shfl(x, 63, 64);
        if (i < NB) blk[i] = x - orig + carry;   // exclusive
        carry += total;
    }
}

// per-block exclusive scan + block offset -> rowPtr
__global__ void scanC(const int* __restrict__ counts, const int* __restrict__ blkOff,
                      int* __restrict__ rowPtr) {
    int i = blockIdx.x * 256 + threadIdx.x;
    int c = (i < NNODES) ? counts[i] : 0;
    int lane = threadIdx.x & 63, w = threadIdx.x >> 6;
    int x = c;
    #pragma unroll
    for (int d = 1; d < 64; d <<= 1) {
        int t = __shfl_up(x, d, 64);
        if (lane >= d) x += t;
    }
    __shared__ int wsum[4];
    if (lane == 63) wsum[w] = x;
    __syncthreads();
    int off = blkOff[blockIdx.x];
    for (int k = 0; k < w; ++k) off += wsum[k];
    if (i < NNODES) rowPtr[i] = off + x - c;     // exclusive
    if (blockIdx.x == 0 && threadIdx.x == 0) rowPtr[NNODES] = NEDGES;
}

// scatter edges into CSR order; fill[] must be zeroed
__global__ void scatter_kernel(const int* __restrict__ rows, const int* __restrict__ cols,
                               const float* __restrict__ vals,
                               const int* __restrict__ rowPtr, int* __restrict__ fill,
                               int2* __restrict__ csr) {
    int e = blockIdx.x * blockDim.x + threadIdx.x;
    if (e >= NEDGES) return;
    int r = rows[e];
    int pos = rowPtr[r] + atomicAdd(&fill[r], 1);
    csr[pos] = make_int2(cols[e], __float_as_int(vals[e]));
}

// --- SpMM: one 16-lane quarter-wave per row, float4 slice per lane ------

__global__ void spmm_csr(const int* __restrict__ rowPtr, const int2* __restrict__ csr,
                         const float* __restrict__ cur, float* __restrict__ nxt,
                         float* __restrict__ acc, int writeNext) {
    int gtid = blockIdx.x * blockDim.x + threadIdx.x;
    int row = gtid >> 4;
    int t   = gtid & 15;
    if (row >= NNODES) return;
    int beg = rowPtr[row], end = rowPtr[row + 1];
    float4 s = make_float4(0.f, 0.f, 0.f, 0.f);
    int e = beg;
    for (; e + 1 < end; e += 2) {            // 2x unroll for gather ILP
        int2 p0 = csr[e];
        int2 p1 = csr[e + 1];
        float v0 = __int_as_float(p0.y);
        float v1 = __int_as_float(p1.y);
        float4 x0 = ((const float4*)(cur + (long)p0.x * EMB))[t];
        float4 x1 = ((const float4*)(cur + (long)p1.x * EMB))[t];
        s.x += v0 * x0.x; s.y += v0 * x0.y; s.z += v0 * x0.z; s.w += v0 * x0.w;
        s.x += v1 * x1.x; s.y += v1 * x1.y; s.z += v1 * x1.z; s.w += v1 * x1.w;
    }
    if (e < end) {
        int2 p = csr[e];
        float v = __int_as_float(p.y);
        float4 x = ((const float4*)(cur + (long)p.x * EMB))[t];
        s.x += v * x.x; s.y += v * x.y; s.z += v * x.z; s.w += v * x.w;
    }
    long o4 = (long)row * (EMB / 4) + t;
    if (writeNext) ((float4*)nxt)[o4] = s;
    float4 a = ((const float4*)acc)[o4];
    a.x += s.x; a.y += s.y; a.z += s.z; a.w += s.w;
    ((float4*)acc)[o4] = a;
}

// One wave per batch element; lane = embedding dim. final = acc/4 -> /16 on dot.
__global__ void score_kernel(const int* __restrict__ users,
                             const int* __restrict__ pos_items,
                             const int* __restrict__ neg_items,
                             const float* __restrict__ acc,
                             float* __restrict__ out) {
    int gtid = blockIdx.x * blockDim.x + threadIdx.x;
    int wave = gtid >> 6;
    int lane = threadIdx.x & 63;
    if (wave >= BATCH) return;
    int u = users[wave];
    int p = pos_items[wave] + NUM_USERS;
    int n = neg_items[wave] + NUM_USERS;
    float ue = acc[(long)u * EMB + lane];
    float pe = acc[(long)p * EMB + lane];
    float ne = acc[(long)n * EMB + lane];
    float ps = ue * pe;
    float ns = ue * ne;
    #pragma unroll
    for (int off = 32; off > 0; off >>= 1) {
        ps += __shfl_down(ps, off, 64);
        ns += __shfl_down(ns, off, 64);
    }
    if (lane == 0) {
        out[wave]         = ps * 0.0625f;
        out[BATCH + wave] = ns * 0.0625f;
    }
}

extern "C" void kernel_launch(void* const* d_in, const int* in_sizes, int n_in,
                              void* d_out, int out_size, void* d_ws, size_t ws_size,
                              hipStream_t stream) {
    const int*   users = (const int*)d_in[0];
    const int*   pos   = (const int*)d_in[1];
    const int*   neg   = (const int*)d_in[2];
    const int*   rows  = (const int*)d_in[3];
    const int*   cols  = (const int*)d_in[4];
    const float* vals  = (const float*)d_in[5];
    const float* uemb  = (const float*)d_in[6];
    const float* iemb  = (const float*)d_in[7];
    float* out = (float*)d_out;

    const size_t bufElems = (size_t)NNODES * EMB;       // 9.6M floats
    float* bufA   = (float*)d_ws;                       // cur
    float* bufB   = bufA + bufElems;                    // next
    float* acc    = bufB + bufElems;                    // accumulator
    int*   rowPtr = (int*)(acc + bufElems);             // NNODES+1 (padded to 150016)
    int*   counts = rowPtr + 150016;                    // NNODES (also reused as fill)
    int*   blkSums= counts + NNODES;                    // NB (padded to 1024)
    int2*  csr    = (int2*)(blkSums + 1024);            // NEDGES int2 (8B-aligned)

    // CSR build
    hipMemsetAsync(counts, 0, NNODES * sizeof(int), stream);
    hist_kernel<<<(NEDGES + 255) / 256, 256, 0, stream>>>(rows, counts);
    scanA<<<NB, 256, 0, stream>>>(counts, blkSums);
    scanB<<<1, 64, 0, stream>>>(blkSums);
    scanC<<<NB, 256, 0, stream>>>(counts, blkSums, rowPtr);
    hipMemsetAsync(counts, 0, NNODES * sizeof(int), stream);
    scatter_kernel<<<(NEDGES + 255) / 256, 256, 0, stream>>>(rows, cols, vals, rowPtr, counts, csr);

    // init cur/acc
    const long n4 = (long)bufElems / 4;
    init_kernel<<<(int)((n4 + 255) / 256), 256, 0, stream>>>(uemb, iemb, bufA, acc);

    // 3 propagation layers
    float* cur = bufA;
    float* nxt = bufB;
    for (int l = 0; l < 3; ++l) {
        const long nth = (long)NNODES * 16;
        spmm_csr<<<(int)((nth + 255) / 256), 256, 0, stream>>>(rowPtr, csr, cur, nxt, acc, l < 2);
        float* tmp = cur; cur = nxt; nxt = tmp;
    }

    score_kernel<<<(BATCH * 64) / 256, 256, 0, stream>>>(users, pos, neg, acc, out);
}